// Round 3
// baseline (352.150 us; speedup 1.0000x reference)
//
#include <hip/hip_runtime.h>

typedef unsigned long long u64;

// ws layout (float offsets unless noted):
#define OFF_A      0        // 510 floats: -0.5*||c||^2 per combo, level-major (off_L = 2^L-2)
#define OFF_DT     512      // dT[c*8+s] = w[r1[s]][c]-w[r0[s]][c]
#define OFF_V0T    1536     // v0T[c*8+s] = w[r0[s]][c]
#define OFF_BASET  2560     // baseT[(L-1)*128+c] = sum_{s<=L} w[r0[s]][c]
#define OFF_IDX_BYTES 16384 // u64 packed indices per position (65536 * 8B)
#define OFF_PART_F    135168 // float offset of partial[8][1024] block sums = (16384+65536*8)/4

__device__ __forceinline__ float warp_sum(float v) {
  #pragma unroll
  for (int off = 32; off > 0; off >>= 1) v += __shfl_down(v, off);
  return v;
}

// ---------------- Kernel A: build codebook tables (ws re-poisoned every launch) -----------
__global__ __launch_bounds__(64) void build_tables(const float* __restrict__ w,
                                                   float* __restrict__ wsf) {
  const int r0[8] = {0, 3, 4, 5, 6, 7, 8, 9};
  int e = blockIdx.x;
  int t = threadIdx.x;
  if (e < 510) {
    int ep2 = e + 2;
    int L = 31 - __clz(ep2);        // level 1..8
    int i = ep2 - (1 << L);         // combo index, b1 = MSB
    float acc = 0.f;
    #pragma unroll
    for (int half = 0; half < 2; ++half) {
      int cc = t + half * 64;
      float v = 0.f;
      for (int s = 0; s < L; ++s) {
        int b = (i >> (L - 1 - s)) & 1;
        v += w[(r0[s] + b) * 128 + cc];
      }
      acc += v * v;
    }
    acc = warp_sum(acc);
    if (t == 0) wsf[OFF_A + e] = -0.5f * acc;
  } else {
    #pragma unroll
    for (int half = 0; half < 2; ++half) {
      int cc = t + half * 64;
      float basesum = 0.f;
      #pragma unroll
      for (int s = 0; s < 8; ++s) {
        float w0 = w[r0[s] * 128 + cc];
        float w1 = w[(r0[s] + 1) * 128 + cc];
        wsf[OFF_V0T + cc * 8 + s] = w0;
        wsf[OFF_DT + cc * 8 + s] = w1 - w0;
        basesum += w0;
        wsf[OFF_BASET + s * 128 + cc] = basesum;
      }
    }
  }
}

// ---------------- Guaranteed-unroll level search (all indices compile-time) ---------------
template <int L, int I, int N>
struct SU {
  static __device__ __forceinline__ void run(const float* Al, const float* T,
                                             const float* S, float& bs, int& bi) {
    float dot;
    if constexpr (L <= 4) {
      dot = T[I << (4 - L)];
    } else {
      dot = T[I >> (L - 4)] + S[(I & ((1 << (L - 4)) - 1)) << (8 - L)];
    }
    float sc = dot + Al[I];
    if (sc > bs) { bs = sc; bi = I; }   // strict > keeps lowest index on ties
    SU<L, I + 1, N>::run(Al, T, S, bs, bi);
  }
};
template <int L, int N>
struct SU<L, N, N> {
  static __device__ __forceinline__ void run(const float*, const float*, const float*,
                                             float&, int&) {}
};

template <int L>
__device__ __forceinline__ void search_level(const float* Al_base, const float* T,
                                             const float* S, float& bestsc, int& bestidx) {
  const float* Al = Al_base + ((1 << L) - 2);
  float bs = -3.4e38f;
  int bi = 0;
  SU<L, 0, (1 << L)>::run(Al, T, S, bs, bi);
  bestsc = bs;
  bestidx = bi;
}

// ---------------- Kernel B: 4 threads/position, LDS tables, split-level argmax ------------
__global__ __launch_bounds__(256) void search_kernel(const float* __restrict__ in,
                                                     const float* __restrict__ tbl,
                                                     float* __restrict__ partial,
                                                     u64* __restrict__ idxp) {
  __shared__ float dTl[1024];
  __shared__ float v0l[1024];
  __shared__ float Al[512];
  __shared__ float part[256][17];
  __shared__ float lsc[4][64];   // level 5,6,7,8 best scores
  __shared__ int   lix[4][64];   // level 5,6,7,8 best indices

  int tid = threadIdx.x;
  for (int i = tid; i < 1024; i += 256) { dTl[i] = tbl[OFF_DT + i]; v0l[i] = tbl[OFF_V0T + i]; }
  if (tid < 255) { Al[tid] = tbl[OFF_A + tid]; Al[tid + 255] = tbl[OFF_A + tid + 255]; }
  __syncthreads();

  int q = tid >> 6;               // channel quarter 0..3
  int posl = tid & 63;            // position within block
  int gpos = blockIdx.x * 64 + posl;
  int b = gpos >> 12;
  int hw = gpos & 4095;
  const float* xp = in + ((size_t)b << 19) + ((size_t)(q * 32) << 12) + hw;

  float qq[8], uu[8];
  #pragma unroll
  for (int k = 0; k < 8; ++k) { qq[k] = 0.f; uu[k] = 0.f; }
  float xx = 0.f;
  int cbase = q * 32;
  float xv[16];
  #pragma unroll
  for (int g = 0; g < 2; ++g) {
    #pragma unroll
    for (int j = 0; j < 16; ++j) xv[j] = xp[(size_t)(g * 16 + j) << 12];  // MLP = 16
    #pragma unroll
    for (int j = 0; j < 16; ++j) {
      float x = xv[j];
      int c = cbase + g * 16 + j;
      xx = fmaf(x, x, xx);
      #pragma unroll
      for (int k = 0; k < 8; ++k) {
        qq[k] = fmaf(x, dTl[c * 8 + k], qq[k]);   // wave-uniform LDS -> broadcast
        uu[k] = fmaf(x, v0l[c * 8 + k], uu[k]);
      }
    }
  }

  // exchange partial dots across the 4 quarters
  #pragma unroll
  for (int k = 0; k < 8; ++k) { part[tid][k] = qq[k]; part[tid][8 + k] = uu[k]; }
  part[tid][16] = xx;
  __syncthreads();
  #pragma unroll
  for (int p = 1; p < 4; ++p) {
    int ptn = tid ^ (p << 6);
    #pragma unroll
    for (int k = 0; k < 8; ++k) { qq[k] += part[ptn][k]; uu[k] += part[ptn][8 + k]; }
    xx += part[ptn][16];
  }

  // subset-sum tables: T over stages 1..4 (bit3<->stage1), S over stages 5..8
  float T[16], S[16];
  #pragma unroll
  for (int h = 0; h < 16; ++h) {
    float tv = 0.f, sv = 0.f;
    if (h & 8) { tv += qq[0]; sv += qq[4]; }
    if (h & 4) { tv += qq[1]; sv += qq[5]; }
    if (h & 2) { tv += qq[2]; sv += qq[6]; }
    if (h & 1) { tv += qq[3]; sv += qq[7]; }
    T[h] = tv; S[h] = sv;
  }

  // split the 510-combo search across quarters: q0:L1-4(30) q1:L5-6(96) q2:L7(128) q3:L8(256)
  float bsc[4];
  int bix[4];
  if (q == 3) {
    float bs; int bi;
    search_level<8>(Al, T, S, bs, bi);
    lsc[3][posl] = bs; lix[3][posl] = bi;
  } else if (q == 2) {
    float bs; int bi;
    search_level<7>(Al, T, S, bs, bi);
    lsc[2][posl] = bs; lix[2][posl] = bi;
  } else if (q == 1) {
    float bs; int bi;
    search_level<5>(Al, T, S, bs, bi);
    lsc[0][posl] = bs; lix[0][posl] = bi;
    search_level<6>(Al, T, S, bs, bi);
    lsc[1][posl] = bs; lix[1][posl] = bi;
  } else {
    search_level<1>(Al, T, S, bsc[0], bix[0]);
    search_level<2>(Al, T, S, bsc[1], bix[1]);
    search_level<3>(Al, T, S, bsc[2], bix[2]);
    search_level<4>(Al, T, S, bsc[3], bix[3]);
  }
  __syncthreads();

  if (q == 0) {                    // wave 0 finalizes: pack indices + losses
    float s5 = lsc[0][posl], s6 = lsc[1][posl], s7 = lsc[2][posl], s8 = lsc[3][posl];
    int i5 = lix[0][posl], i6 = lix[1][posl], i7 = lix[2][posl], i8 = lix[3][posl];
    u64 pk = (u64)bix[0] | ((u64)bix[1] << 1) | ((u64)bix[2] << 3) | ((u64)bix[3] << 6) |
             ((u64)i5 << 10) | ((u64)i6 << 15) | ((u64)i7 << 21) | ((u64)i8 << 28);
    idxp[gpos] = pk;
    float ball[8] = {bsc[0], bsc[1], bsc[2], bsc[3], s5, s6, s7, s8};
    float P0 = 0.f;
    #pragma unroll
    for (int l = 0; l < 8; ++l) {
      P0 += uu[l];                               // x . base_L
      float sse = xx - 2.f * (P0 + ball[l]);     // ||x - q||^2
      sse = warp_sum(sse);
      if (tid == 0) partial[l * 1024 + blockIdx.x] = sse;
    }
  }
}

// ---------------- Kernel C: reconstruct q with float4 stores, final loss reduce -----------
template <int LV>
__device__ __forceinline__ void write_level(const float* dTl, const float* btl,
                                            const u64* __restrict__ idxp, int pos,
                                            float4* __restrict__ op) {
  constexpr int SHv = (LV == 1 ? 0 : LV == 2 ? 1 : LV == 3 ? 3 : LV == 4 ? 6 :
                       LV == 5 ? 10 : LV == 6 ? 15 : LV == 7 ? 21 : 28);
  float bf[4][LV];
  #pragma unroll
  for (int p = 0; p < 4; ++p) {
    u64 pk = idxp[pos + p];
    int idx = (int)((pk >> SHv) & ((1u << LV) - 1));
    #pragma unroll
    for (int s = 0; s < LV; ++s) bf[p][s] = (float)((idx >> (LV - 1 - s)) & 1);
  }
  #pragma unroll 2
  for (int c = 0; c < 128; ++c) {
    float bt = btl[c];
    float dv[LV];
    #pragma unroll
    for (int s = 0; s < LV; ++s) dv[s] = dTl[c * 8 + s];   // broadcast LDS
    float q0 = bt, q1 = bt, q2 = bt, q3 = bt;
    #pragma unroll
    for (int s = 0; s < LV; ++s) {
      q0 = fmaf(bf[0][s], dv[s], q0);
      q1 = fmaf(bf[1][s], dv[s], q1);
      q2 = fmaf(bf[2][s], dv[s], q2);
      q3 = fmaf(bf[3][s], dv[s], q3);
    }
    float4 r; r.x = q0; r.y = q1; r.z = q2; r.w = q3;
    op[(size_t)c << 10] = r;                     // 1 KB/wave-instruction, coalesced
  }
}

__global__ __launch_bounds__(256) void write_kernel(const float* __restrict__ tbl,
                                                    const u64* __restrict__ idxp,
                                                    float* __restrict__ out) {
  __shared__ float dTl[1024];
  __shared__ float btl[128];
  int blk = blockIdx.x;
  int L = blk >> 6;                 // 0..7, level LV = L+1
  for (int i = threadIdx.x; i < 1024; i += 256) dTl[i] = tbl[OFF_DT + i];
  if (threadIdx.x < 128) btl[threadIdx.x] = tbl[OFF_BASET + L * 128 + threadIdx.x];
  __syncthreads();

  // deterministic final loss reduction by wave 0 of block 0 (hidden under store stream)
  if (blk == 0 && threadIdx.x < 64) {
    const float CO[8] = {1.5f, 1.2f, 1.0f, 0.9f, 0.82f, 0.69f, 0.65f, 0.56f};
    const float* partial = tbl + OFF_PART_F;
    int t = threadIdx.x;
    int l = t >> 3;
    int j = t & 7;
    float s = 0.f;
    #pragma unroll 4
    for (int k = 0; k < 128; ++k) s += partial[l * 1024 + j + k * 8];
    s += __shfl_down(s, 4);
    s += __shfl_down(s, 2);
    s += __shfl_down(s, 1);
    if (j == 0)
      out[67108864ull + l] = (CO[l] + 0.4f) * s * (1.0f / 8388608.0f);
  }

  int g = (blk & 63) * 256 + threadIdx.x;   // float4-group id within level, 0..16383
  int pos = g << 2;                          // base position (4 per thread)
  int bb = pos >> 12;
  int hw = pos & 4095;
  float4* op = (float4*)(out + (((size_t)(L * 16 + bb)) << 19) + hw);
  switch (L) {
    case 0: write_level<1>(dTl, btl, idxp, pos, op); break;
    case 1: write_level<2>(dTl, btl, idxp, pos, op); break;
    case 2: write_level<3>(dTl, btl, idxp, pos, op); break;
    case 3: write_level<4>(dTl, btl, idxp, pos, op); break;
    case 4: write_level<5>(dTl, btl, idxp, pos, op); break;
    case 5: write_level<6>(dTl, btl, idxp, pos, op); break;
    case 6: write_level<7>(dTl, btl, idxp, pos, op); break;
    case 7: write_level<8>(dTl, btl, idxp, pos, op); break;
  }
}

extern "C" void kernel_launch(void* const* d_in, const int* in_sizes, int n_in,
                              void* d_out, int out_size, void* d_ws, size_t ws_size,
                              hipStream_t stream) {
  const float* in = (const float*)d_in[0];   // (16,128,64,64) fp32
  const float* w  = (const float*)d_in[1];   // (256,128) fp32
  float* wsf = (float*)d_ws;
  u64* idxp = (u64*)((char*)d_ws + OFF_IDX_BYTES);
  float* partial = wsf + OFF_PART_F;
  float* out = (float*)d_out;

  build_tables<<<511, 64, 0, stream>>>(w, wsf);
  search_kernel<<<1024, 256, 0, stream>>>(in, wsf, partial, idxp);
  write_kernel<<<512, 256, 0, stream>>>(wsf, idxp, out);
}